// Round 6
// baseline (190.063 us; speedup 1.0000x reference)
//
#include <hip/hip_runtime.h>
#include <math.h>

// Tropical (max-plus) depthwise 3x3 conv, stride=1, pad=1, dil=1.
// x: (B=8, C=64, H=224, W=224) fp32; kernel: (64,1,3,3) fp32; out = x shape.
//
// R7: same 8-rows/thread shape as R6, but the load block is BRANCH-FREE
// (clamped addresses + cndmask fixups to -inf) and __launch_bounds__(256,4)
// lifts the VGPR cap to 128. R6's counters showed VGPR_Count=48 — too few
// to hold the 10-row batch (needs ~60 data regs), so the compiler silently
// re-chunked the loads into a rolling window and stayed latency-bound
// (63 us vs ~26 us HBM floor, VALUBusy ~15%). The 10 per-row boundary
// branches also blocked load clustering. Both removed here: 30 unconditional
// loads issue back-to-back; fine-grained vmcnt lets row-0 compute start
// after 3 rows land.
//   + XCD-aware bijective block swizzle (grid 3136 = 8 x 392): adjacent
//     row-groups share 2 halo rows -> same-XCD L2 hits.

#define H_DIM 224
#define W_DIM 224
#define W4    56            // W/4
#define ROWS  8             // output rows per thread
#define GR    28            // H/ROWS row-groups
#define C_DIM 64
#define NXCD  8

__global__ __launch_bounds__(256, 4) void tropical_conv_kernel(
    const float* __restrict__ x,
    const float* __restrict__ kern,
    float* __restrict__ out,
    int total)   // total threads = B*C*GR*W4 = 802,816 (grid 3136 blocks)
{
    int bid  = blockIdx.x;
    int cpx  = gridDim.x >> 3;                 // blocks per XCD chunk
    int swz  = (bid & (NXCD - 1)) * cpx + (bid >> 3);
    int idx  = swz * blockDim.x + threadIdx.x;
    if (idx >= total) return;

    const float NEG = -INFINITY;

    int j4 = idx % W4;          // float4 index within the row
    int t  = idx / W4;
    int g  = t % GR;            // 8-row group
    int bc = t / GR;            // fused batch*channel plane
    int c  = bc & (C_DIM - 1);

    const float* kc = kern + c * 9;
    float k00 = kc[0], k01 = kc[1], k02 = kc[2];
    float k10 = kc[3], k11 = kc[4], k12 = kc[5];
    float k20 = kc[6], k21 = kc[7], k22 = kc[8];

    const float* plane  = x   + (size_t)bc * (H_DIM * W_DIM);
    float*       oplane = out + (size_t)bc * (H_DIM * W_DIM);
    int j0 = j4 * 4;
    int i0 = g * ROWS;

    // Horizontal halo columns, clamped into the row (fixup to NEG below).
    bool lok = (j4 > 0);
    bool rok = (j4 < W4 - 1);
    int  lfc = lok ? j0 - 1 : 0;
    int  rgc = rok ? j0 + 4 : W_DIM - 1;

    // ---- Branch-free load block: 30 unconditional loads ----
    float4 rv[ROWS + 2];
    float  lf[ROWS + 2], rg[ROWS + 2];
    #pragma unroll
    for (int rr = 0; rr < ROWS + 2; ++rr) {
        int r  = i0 - 1 + rr;
        int rc = r < 0 ? 0 : (r > H_DIM - 1 ? H_DIM - 1 : r);   // clamp (only rr=0/9 can clip)
        const float* row = plane + rc * W_DIM;
        rv[rr] = *(const float4*)(row + j0);
        lf[rr] = row[lfc];
        rg[rr] = row[rgc];
    }

    // ---- Fixups to the tropical neutral element (selects, no branches) ----
    bool top = (g == 0);        // rr=0 is row -1
    bool bot = (g == GR - 1);   // rr=ROWS+1 is row 224
    rv[0].x = top ? NEG : rv[0].x;
    rv[0].y = top ? NEG : rv[0].y;
    rv[0].z = top ? NEG : rv[0].z;
    rv[0].w = top ? NEG : rv[0].w;
    rv[ROWS + 1].x = bot ? NEG : rv[ROWS + 1].x;
    rv[ROWS + 1].y = bot ? NEG : rv[ROWS + 1].y;
    rv[ROWS + 1].z = bot ? NEG : rv[ROWS + 1].z;
    rv[ROWS + 1].w = bot ? NEG : rv[ROWS + 1].w;
    #pragma unroll
    for (int rr = 0; rr < ROWS + 2; ++rr) {
        bool rowdead = (rr == 0 && top) || (rr == ROWS + 1 && bot);
        lf[rr] = (lok && !rowdead) ? lf[rr] : NEG;
        rg[rr] = (rok && !rowdead) ? rg[rr] : NEG;
    }

    // ---- Compute: 8 output rows ----
    #pragma unroll
    for (int o = 0; o < ROWS; ++o) {
        float4 acc = make_float4(NEG, NEG, NEG, NEG);
        #pragma unroll
        for (int ki = 0; ki < 3; ++ki) {
            int rr = o + ki;            // compile-time constant after unroll
            float t0 = (ki == 0) ? k00 : (ki == 1) ? k10 : k20;
            float t1 = (ki == 0) ? k01 : (ki == 1) ? k11 : k21;
            float t2 = (ki == 0) ? k02 : (ki == 1) ? k12 : k22;
            float4 a = rv[rr];
            acc.x = fmaxf(acc.x, fmaxf(fmaxf(lf[rr] + t0, a.x + t1), a.y    + t2));
            acc.y = fmaxf(acc.y, fmaxf(fmaxf(a.x    + t0, a.y + t1), a.z    + t2));
            acc.z = fmaxf(acc.z, fmaxf(fmaxf(a.y    + t0, a.z + t1), a.w    + t2));
            acc.w = fmaxf(acc.w, fmaxf(fmaxf(a.z    + t0, a.w + t1), rg[rr] + t2));
        }
        *(float4*)(oplane + (size_t)(i0 + o) * W_DIM + j0) = acc;
    }
}

extern "C" void kernel_launch(void* const* d_in, const int* in_sizes, int n_in,
                              void* d_out, int out_size, void* d_ws, size_t ws_size,
                              hipStream_t stream) {
    const float* x    = (const float*)d_in[0];
    const float* kern = (const float*)d_in[1];
    float* out        = (float*)d_out;

    const int total = 8 * C_DIM * GR * W4;   // 802,816 threads
    const int block = 256;
    const int grid  = (total + block - 1) / block;  // 3136 blocks (8 x 392)
    tropical_conv_kernel<<<grid, block, 0, stream>>>(x, kern, out, total);
}

// Round 8
// 185.369 us; speedup vs baseline: 1.0253x; 1.0253x over previous
//
#include <hip/hip_runtime.h>
#include <math.h>

// Tropical (max-plus) depthwise 3x3 conv, stride=1, pad=1, dil=1.
// x: (B=8, C=64, H=224, W=224) fp32; kernel: (64,1,3,3) fp32; out = x shape.
//
// R9 = R8 resubmitted verbatim (bench died on container infra, not kernel).
//
// R8: wave-aligned row strips + shuffle halos + forced load clustering.
//   - One WAVE owns a 4-output-row x full-width strip. Lanes 0..55 each
//     hold one float4 of a row (56*4 = 224); lanes 56..63 are clamped
//     duplicates (same cache lines, no extra traffic, masked on store).
//   - Halos come from cross-lane shuffles (shfl_up of rv.w / shfl_down of
//     rv.x), NOT scalar global loads: VMEM loads per strip drop 18 -> 6,
//     each a single contiguous 896B wave-aligned burst. R7's counters
//     (VGPR stuck at 48, dur flat ~62us, VALUBusy 18%) showed the
//     scalar-halo + chunked-load structure was the serializer candidate.
//   - sched_barrier(0) after the 6-load block: only 24 data VGPRs needed,
//     so the scheduler has no pressure excuse not to cluster all 6 loads
//     (counted vmcnt then overlaps fixups/shuffles with the loads).
//   - 28,672 waves (7168 blocks) = 3.5x resident capacity; VGPR <= 64
//     keeps 8 waves/SIMD -> occupancy and latency-hiding both up.
//   - XCD-aware bijective swizzle kept (FETCH 59->50 MB in R7).

#define H_DIM 224
#define W_DIM 224
#define SR    4             // output rows per wave strip
#define SPP   56            // strips per plane (224/4)
#define C_DIM 64
#define NXCD  8

__global__ __launch_bounds__(256) void tropical_conv_kernel(
    const float* __restrict__ x,
    const float* __restrict__ kern,
    float* __restrict__ out)
{
    // Bijective XCD swizzle: grid 7168 = 8 x 896.
    int bid  = blockIdx.x;
    int cpx  = gridDim.x >> 3;
    int swz  = (bid & (NXCD - 1)) * cpx + (bid >> 3);

    int lane = threadIdx.x & 63;
    int wid  = swz * 4 + (threadIdx.x >> 6);   // global wave id, 0..28671

    int s  = wid % SPP;          // strip within plane
    int bc = wid / SPP;          // fused batch*channel plane
    int c  = bc & (C_DIM - 1);

    const float* kc = kern + c * 9;
    float k00 = kc[0], k01 = kc[1], k02 = kc[2];
    float k10 = kc[3], k11 = kc[4], k12 = kc[5];
    float k20 = kc[6], k21 = kc[7], k22 = kc[8];

    const float NEG = -INFINITY;

    const float* plane  = x   + (size_t)bc * (H_DIM * W_DIM);
    float*       oplane = out + (size_t)bc * (H_DIM * W_DIM);

    int i0  = s * SR;
    int cl  = (lane < 56) ? lane : 55;     // clamped column slot
    int col = cl * 4;

    // ---- 6 contiguous wave-aligned loads (rows i0-1 .. i0+4, clamped) ----
    float4 rv[SR + 2];
    #pragma unroll
    for (int rr = 0; rr < SR + 2; ++rr) {
        int r  = i0 - 1 + rr;
        int rc = r < 0 ? 0 : (r > H_DIM - 1 ? H_DIM - 1 : r);
        rv[rr] = *(const float4*)(plane + (size_t)rc * W_DIM + col);
    }
    __builtin_amdgcn_sched_barrier(0);   // pin: all 6 loads issue first

    // ---- dead-row fixup (rows -1 / 224 -> tropical neutral) ----
    bool top = (s == 0);
    bool bot = (s == SPP - 1);
    rv[0].x = top ? NEG : rv[0].x;
    rv[0].y = top ? NEG : rv[0].y;
    rv[0].z = top ? NEG : rv[0].z;
    rv[0].w = top ? NEG : rv[0].w;
    rv[SR + 1].x = bot ? NEG : rv[SR + 1].x;
    rv[SR + 1].y = bot ? NEG : rv[SR + 1].y;
    rv[SR + 1].z = bot ? NEG : rv[SR + 1].z;
    rv[SR + 1].w = bot ? NEG : rv[SR + 1].w;

    // ---- halos via cross-lane shuffle (no memory) ----
    float lf[SR + 2], rg[SR + 2];
    #pragma unroll
    for (int rr = 0; rr < SR + 2; ++rr) {
        float up = __shfl_up(rv[rr].w, 1);     // lane-1's last element
        float dn = __shfl_down(rv[rr].x, 1);   // lane+1's first element
        lf[rr] = (lane > 0)  ? up : NEG;       // lane 0 = left pad
        rg[rr] = (lane < 55) ? dn : NEG;       // lane 55 = right pad
    }

    // ---- compute 4 output rows ----
    #pragma unroll
    for (int o = 0; o < SR; ++o) {
        float4 acc = make_float4(NEG, NEG, NEG, NEG);
        #pragma unroll
        for (int ki = 0; ki < 3; ++ki) {
            int rr = o + ki;            // compile-time constant after unroll
            float t0 = (ki == 0) ? k00 : (ki == 1) ? k10 : k20;
            float t1 = (ki == 0) ? k01 : (ki == 1) ? k11 : k21;
            float t2 = (ki == 0) ? k02 : (ki == 1) ? k12 : k22;
            float4 a = rv[rr];
            acc.x = fmaxf(acc.x, fmaxf(fmaxf(lf[rr] + t0, a.x + t1), a.y    + t2));
            acc.y = fmaxf(acc.y, fmaxf(fmaxf(a.x    + t0, a.y + t1), a.z    + t2));
            acc.z = fmaxf(acc.z, fmaxf(fmaxf(a.y    + t0, a.z + t1), a.w    + t2));
            acc.w = fmaxf(acc.w, fmaxf(fmaxf(a.z    + t0, a.w + t1), rg[rr] + t2));
        }
        if (lane < 56) {
            *(float4*)(oplane + (size_t)(i0 + o) * W_DIM + col) = acc;
        }
    }
}

extern "C" void kernel_launch(void* const* d_in, const int* in_sizes, int n_in,
                              void* d_out, int out_size, void* d_ws, size_t ws_size,
                              hipStream_t stream) {
    const float* x    = (const float*)d_in[0];
    const float* kern = (const float*)d_in[1];
    float* out        = (float*)d_out;

    // waves = B*C*SPP = 8*64*56 = 28,672 ; 4 waves/block -> 7168 blocks.
    const int grid  = 8 * C_DIM * SPP / 4;
    const int block = 256;
    tropical_conv_kernel<<<grid, block, 0, stream>>>(x, kern, out);
}